// Round 1
// baseline (872.274 us; speedup 1.0000x reference)
//
#include <hip/hip_runtime.h>
#include <hip/hip_bf16.h>
#include <math.h>

#define NN 100000
#define NE 1000000

// ============================== CSR build ==============================

__global__ void hist_kernel(const int* __restrict__ dst, int* __restrict__ deg, int E) {
    int i = blockIdx.x * blockDim.x + threadIdx.x;
    if (i < E) atomicAdd(&deg[dst[i]], 1);
}

__global__ void scan_local(const int* __restrict__ deg, int* __restrict__ rowptr,
                           int* __restrict__ bsum, int N) {
    __shared__ int s[256];
    int i = blockIdx.x * 256 + threadIdx.x;
    int v = (i < N) ? deg[i] : 0;
    s[threadIdx.x] = v;
    __syncthreads();
    #pragma unroll
    for (int off = 1; off < 256; off <<= 1) {
        int t = (threadIdx.x >= off) ? s[threadIdx.x - off] : 0;
        __syncthreads();
        s[threadIdx.x] += t;
        __syncthreads();
    }
    if (i < N) rowptr[i + 1] = s[threadIdx.x];
    if (threadIdx.x == 255) bsum[blockIdx.x] = s[255];
}

__global__ void scan_bsum(int* __restrict__ bsum, int NB) {
    __shared__ int s[512];
    int v = (threadIdx.x < NB) ? bsum[threadIdx.x] : 0;
    s[threadIdx.x] = v;
    __syncthreads();
    for (int off = 1; off < 512; off <<= 1) {
        int t = (threadIdx.x >= off) ? s[threadIdx.x - off] : 0;
        __syncthreads();
        s[threadIdx.x] += t;
        __syncthreads();
    }
    if (threadIdx.x < NB) bsum[threadIdx.x] = s[threadIdx.x] - v;  // exclusive
}

__global__ void scan_add(int* __restrict__ rowptr, const int* __restrict__ bsum, int N) {
    int i = blockIdx.x * blockDim.x + threadIdx.x;
    if (i < N) rowptr[i + 1] += bsum[i >> 8];
    if (i == 0) rowptr[0] = 0;
}

__global__ void scatter_kernel(const int* __restrict__ src, const int* __restrict__ dst,
                               const int* __restrict__ rowptr, int* __restrict__ cnt,
                               int* __restrict__ csrc, int E) {
    int i = blockIdx.x * blockDim.x + threadIdx.x;
    if (i < E) {
        int d = dst[i];
        int pos = rowptr[d] + atomicAdd(&cnt[d], 1);
        csrc[pos] = src[i];
    }
}

// ============================== GEMMs (fp32) ==============================

// C[M,128] = A[M,K] * B[K,128]; block: 256 thr, 64 rows; thread: 8 rows x 4 cols
template<int K>
__global__ __launch_bounds__(256) void gemm_nc128(const float* __restrict__ A,
                                                  const float* __restrict__ B,
                                                  float* __restrict__ C, int M) {
    const int c = threadIdx.x & 31;   // col group -> cols 4c..4c+3
    const int r = threadIdx.x >> 5;   // 0..7
    const int row0 = blockIdx.x * 64;
    float acc[8][4] = {};
    const float* Ap[8];
    #pragma unroll
    for (int i = 0; i < 8; ++i) {
        int row = row0 + r + 8 * i;
        int rr = row < M ? row : M - 1;
        Ap[i] = A + (size_t)rr * K;
    }
    const float* Bp = B + c * 4;
    #pragma unroll 4
    for (int k = 0; k < K; ++k) {
        const float4 b4 = *reinterpret_cast<const float4*>(Bp + (size_t)k * 128);
        #pragma unroll
        for (int i = 0; i < 8; ++i) {
            float a = Ap[i][k];
            acc[i][0] += a * b4.x;
            acc[i][1] += a * b4.y;
            acc[i][2] += a * b4.z;
            acc[i][3] += a * b4.w;
        }
    }
    #pragma unroll
    for (int i = 0; i < 8; ++i) {
        int row = row0 + r + 8 * i;
        if (row < M) {
            float4 o = make_float4(acc[i][0], acc[i][1], acc[i][2], acc[i][3]);
            *reinterpret_cast<float4*>(C + (size_t)row * 128 + c * 4) = o;
        }
    }
}

// C[M,40] = A[M,128] * B[128,40]; block 320 thr (5 waves); thread: 8 rows x 1 col
__global__ __launch_bounds__(320) void gemm_nc40(const float* __restrict__ A,
                                                 const float* __restrict__ B,
                                                 float* __restrict__ C, int M) {
    const int c = threadIdx.x % 40;
    const int r = threadIdx.x / 40;   // 0..7
    const int row0 = blockIdx.x * 64;
    float acc[8] = {};
    const float* Ap[8];
    #pragma unroll
    for (int i = 0; i < 8; ++i) {
        int row = row0 + r + 8 * i;
        int rr = row < M ? row : M - 1;
        Ap[i] = A + (size_t)rr * 128;
    }
    #pragma unroll 4
    for (int k = 0; k < 128; ++k) {
        float b = B[(size_t)k * 40 + c];
        #pragma unroll
        for (int i = 0; i < 8; ++i) acc[i] += Ap[i][k] * b;
    }
    #pragma unroll
    for (int i = 0; i < 8; ++i) {
        int row = row0 + r + 8 * i;
        if (row < M) C[(size_t)row * 40 + c] = acc[i];
    }
}

// ============================== el / er ==============================

// h:[N,128] (4 heads x 32), al/ar flat [128]; wave per node
__global__ __launch_bounds__(256) void elr4(const float* __restrict__ h,
                                            const float* __restrict__ al,
                                            const float* __restrict__ ar,
                                            float* __restrict__ el, float* __restrict__ er, int N) {
    int wid = blockIdx.x * 4 + (threadIdx.x >> 6);
    int lane = threadIdx.x & 63;
    if (wid >= N) return;
    float h0 = h[(size_t)wid * 128 + lane];
    float h1 = h[(size_t)wid * 128 + 64 + lane];
    float pl0 = h0 * al[lane], pl1 = h1 * al[64 + lane];
    float pr0 = h0 * ar[lane], pr1 = h1 * ar[64 + lane];
    #pragma unroll
    for (int o = 16; o >= 1; o >>= 1) {   // reduce within 32-lane halves
        pl0 += __shfl_xor(pl0, o); pl1 += __shfl_xor(pl1, o);
        pr0 += __shfl_xor(pr0, o); pr1 += __shfl_xor(pr1, o);
    }
    if ((lane & 31) == 0) {
        int hd = lane >> 5;   // 0 or 1
        el[wid * 4 + hd]     = pl0;
        el[wid * 4 + 2 + hd] = pl1;
        er[wid * 4 + hd]     = pr0;
        er[wid * 4 + 2 + hd] = pr1;
    }
}

// h:[N,40], al/ar [40]; wave per node
__global__ __launch_bounds__(256) void elr1(const float* __restrict__ h,
                                            const float* __restrict__ al,
                                            const float* __restrict__ ar,
                                            float* __restrict__ el, float* __restrict__ er, int N) {
    int wid = blockIdx.x * 4 + (threadIdx.x >> 6);
    int lane = threadIdx.x & 63;
    if (wid >= N) return;
    float hv = (lane < 40) ? h[(size_t)wid * 40 + lane] : 0.f;
    float pl = (lane < 40) ? hv * al[lane] : 0.f;
    float pr = (lane < 40) ? hv * ar[lane] : 0.f;
    #pragma unroll
    for (int o = 32; o >= 1; o >>= 1) { pl += __shfl_xor(pl, o); pr += __shfl_xor(pr, o); }
    if (lane == 0) { el[wid] = pl; er[wid] = pr; }
}

// ============================== aggregation ==============================

// 4-head GAT aggregation, one wave per dst node, online softmax, fused bias+relu
template<bool RELU>
__global__ __launch_bounds__(256) void agg4(const float* __restrict__ h,
                                            const float* __restrict__ el,
                                            const float* __restrict__ er,
                                            const float* __restrict__ bias,
                                            const int* __restrict__ rowptr,
                                            const int* __restrict__ csrc,
                                            float* __restrict__ out, int N) {
    int wid = blockIdx.x * 4 + (threadIdx.x >> 6);
    int lane = threadIdx.x & 63;
    if (wid >= N) return;
    int beg = rowptr[wid], end = rowptr[wid + 1];
    int hA = lane >> 5;       // head for feature f=lane (0 or 1)
    // feature f=lane+64 belongs to head hA+2
    float erA = er[wid * 4 + hA];
    float erB = er[wid * 4 + 2 + hA];
    float mA = -INFINITY, mB = -INFINITY;
    float sA = 0.f, sB = 0.f, aA = 0.f, aB = 0.f;
    for (int p = beg; p < end; ++p) {
        int sid = csrc[p];
        float eA = el[sid * 4 + hA] + erA;     eA = eA > 0.f ? eA : 0.2f * eA;
        float eB = el[sid * 4 + 2 + hA] + erB; eB = eB > 0.f ? eB : 0.2f * eB;
        float hx0 = h[(size_t)sid * 128 + lane];
        float hx1 = h[(size_t)sid * 128 + 64 + lane];
        float nmA = fmaxf(mA, eA);
        float fA = __expf(mA - nmA);
        float pA = __expf(eA - nmA);
        sA = sA * fA + pA; aA = aA * fA + pA * hx0; mA = nmA;
        float nmB = fmaxf(mB, eB);
        float fB = __expf(mB - nmB);
        float pB = __expf(eB - nmB);
        sB = sB * fB + pB; aB = aB * fB + pB * hx1; mB = nmB;
    }
    float oA = (end > beg) ? aA / sA : 0.f;
    float oB = (end > beg) ? aB / sB : 0.f;
    oA += bias[lane];
    oB += bias[64 + lane];
    if (RELU) { oA = fmaxf(oA, 0.f); oB = fmaxf(oB, 0.f); }
    out[(size_t)wid * 128 + lane] = oA;
    out[(size_t)wid * 128 + 64 + lane] = oB;
}

// single-head aggregation + bias + log_softmax(40), one wave per dst node
__global__ __launch_bounds__(256) void agg1_lsm(const float* __restrict__ h,
                                                const float* __restrict__ el,
                                                const float* __restrict__ er,
                                                const float* __restrict__ bias,
                                                const int* __restrict__ rowptr,
                                                const int* __restrict__ csrc,
                                                float* __restrict__ out, int N) {
    int wid = blockIdx.x * 4 + (threadIdx.x >> 6);
    int lane = threadIdx.x & 63;
    if (wid >= N) return;
    int beg = rowptr[wid], end = rowptr[wid + 1];
    float ern = er[wid];
    float m = -INFINITY, s = 0.f, acc = 0.f;
    for (int p = beg; p < end; ++p) {
        int sid = csrc[p];
        float e = el[sid] + ern; e = e > 0.f ? e : 0.2f * e;
        float hx = (lane < 40) ? h[(size_t)sid * 40 + lane] : 0.f;
        float nm = fmaxf(m, e);
        float f = __expf(m - nm);
        float pe = __expf(e - nm);
        s = s * f + pe; acc = acc * f + pe * hx; m = nm;
    }
    float v = (end > beg) ? acc / s : 0.f;
    v += (lane < 40) ? bias[lane] : 0.f;
    float vv = (lane < 40) ? v : -INFINITY;
    float mx = vv;
    #pragma unroll
    for (int o = 32; o >= 1; o >>= 1) mx = fmaxf(mx, __shfl_xor(mx, o));
    float ex = (lane < 40) ? __expf(v - mx) : 0.f;
    float se = ex;
    #pragma unroll
    for (int o = 32; o >= 1; o >>= 1) se += __shfl_xor(se, o);
    if (lane < 40) out[(size_t)wid * 40 + lane] = v - mx - logf(se);
}

// ============================== launch ==============================

extern "C" void kernel_launch(void* const* d_in, const int* in_sizes, int n_in,
                              void* d_out, int out_size, void* d_ws, size_t ws_size,
                              hipStream_t stream) {
    const float* feat = (const float*)d_in[0];
    const float* W1  = (const float*)d_in[1];
    const float* al1 = (const float*)d_in[2];
    const float* ar1 = (const float*)d_in[3];
    const float* b1  = (const float*)d_in[4];
    const float* W2  = (const float*)d_in[5];
    const float* al2 = (const float*)d_in[6];
    const float* ar2 = (const float*)d_in[7];
    const float* b2  = (const float*)d_in[8];
    const float* W3  = (const float*)d_in[9];
    const float* al3 = (const float*)d_in[10];
    const float* ar3 = (const float*)d_in[11];
    const float* b3  = (const float*)d_in[12];
    const int*   src = (const int*)d_in[13];
    const int*   dst = (const int*)d_in[14];
    float* out = (float*)d_out;
    const int N = NN, E = NE;

    char* ws = (char*)d_ws;
    size_t off = 0;
    auto alloc = [&](size_t bytes) -> char* {
        char* p = ws + off;
        off += (bytes + 255) & ~(size_t)255;
        return p;
    };
    int*   deg    = (int*)alloc((size_t)N * 4);       // also reused as scatter cnt
    int*   rowptr = (int*)alloc((size_t)(N + 1) * 4);
    int*   bsum   = (int*)alloc(512 * 4);
    int*   csrc   = (int*)alloc((size_t)E * 4);
    float* el     = (float*)alloc((size_t)N * 4 * 4);
    float* er     = (float*)alloc((size_t)N * 4 * 4);
    float* hbuf   = (float*)alloc((size_t)N * 128 * 4);
    float* xbuf   = (float*)alloc((size_t)N * 128 * 4);

    // ---- CSR build (reused by all 3 layers) ----
    hipMemsetAsync(deg, 0, (size_t)N * 4, stream);
    hist_kernel<<<(E + 255) / 256, 256, 0, stream>>>(dst, deg, E);
    int NB = (N + 255) / 256;  // 391
    scan_local<<<NB, 256, 0, stream>>>(deg, rowptr, bsum, N);
    scan_bsum<<<1, 512, 0, stream>>>(bsum, NB);
    scan_add<<<(N + 255) / 256, 256, 0, stream>>>(rowptr, bsum, N);
    hipMemsetAsync(deg, 0, (size_t)N * 4, stream);
    scatter_kernel<<<(E + 255) / 256, 256, 0, stream>>>(src, dst, rowptr, deg, csrc, E);

    int gemmGrid = (N + 63) / 64;
    int nodeGrid = (N + 3) / 4;

    // ---- layer 1 ----
    gemm_nc128<256><<<gemmGrid, 256, 0, stream>>>(feat, W1, hbuf, N);
    elr4<<<nodeGrid, 256, 0, stream>>>(hbuf, al1, ar1, el, er, N);
    agg4<true><<<nodeGrid, 256, 0, stream>>>(hbuf, el, er, b1, rowptr, csrc, xbuf, N);

    // ---- layer 2 ----
    gemm_nc128<128><<<gemmGrid, 256, 0, stream>>>(xbuf, W2, hbuf, N);
    elr4<<<nodeGrid, 256, 0, stream>>>(hbuf, al2, ar2, el, er, N);
    agg4<true><<<nodeGrid, 256, 0, stream>>>(hbuf, el, er, b2, rowptr, csrc, xbuf, N);

    // ---- layer 3 (+ fused log_softmax) ----
    gemm_nc40<<<gemmGrid, 320, 0, stream>>>(xbuf, W3, hbuf, N);
    elr1<<<nodeGrid, 256, 0, stream>>>(hbuf, al3, ar3, el, er, N);
    agg1_lsm<<<nodeGrid, 256, 0, stream>>>(hbuf, el, er, b3, rowptr, csrc, out, N);
}

// Round 2
// 629.801 us; speedup vs baseline: 1.3850x; 1.3850x over previous
//
#include <hip/hip_runtime.h>
#include <hip/hip_bf16.h>
#include <math.h>

#define NN 100000
#define NE 1000000

typedef __attribute__((ext_vector_type(8))) short bf16x8;
typedef __attribute__((ext_vector_type(4))) float f32x4;

__device__ __forceinline__ unsigned short f2b(float f) {
    __hip_bfloat16 h = __float2bfloat16(f);
    return *reinterpret_cast<unsigned short*>(&h);
}
__device__ __forceinline__ float b2f(unsigned short u) {
    __hip_bfloat16 h = *reinterpret_cast<__hip_bfloat16*>(&u);
    return __bfloat162float(h);
}

// ============================== CSR build ==============================

__global__ void hist_kernel(const int* __restrict__ dst, int* __restrict__ deg, int E) {
    int i = blockIdx.x * blockDim.x + threadIdx.x;
    if (i < E) atomicAdd(&deg[dst[i]], 1);
}

__global__ void scan_local(const int* __restrict__ deg, int* __restrict__ rowptr,
                           int* __restrict__ bsum, int N) {
    __shared__ int s[256];
    int i = blockIdx.x * 256 + threadIdx.x;
    int v = (i < N) ? deg[i] : 0;
    s[threadIdx.x] = v;
    __syncthreads();
    #pragma unroll
    for (int off = 1; off < 256; off <<= 1) {
        int t = (threadIdx.x >= off) ? s[threadIdx.x - off] : 0;
        __syncthreads();
        s[threadIdx.x] += t;
        __syncthreads();
    }
    if (i < N) rowptr[i + 1] = s[threadIdx.x];
    if (threadIdx.x == 255) bsum[blockIdx.x] = s[255];
}

__global__ void scan_bsum(int* __restrict__ bsum, int NB) {
    __shared__ int s[512];
    int v = (threadIdx.x < NB) ? bsum[threadIdx.x] : 0;
    s[threadIdx.x] = v;
    __syncthreads();
    for (int off = 1; off < 512; off <<= 1) {
        int t = (threadIdx.x >= off) ? s[threadIdx.x - off] : 0;
        __syncthreads();
        s[threadIdx.x] += t;
        __syncthreads();
    }
    if (threadIdx.x < NB) bsum[threadIdx.x] = s[threadIdx.x] - v;  // exclusive
}

__global__ void scan_add(int* __restrict__ rowptr, const int* __restrict__ bsum, int N) {
    int i = blockIdx.x * blockDim.x + threadIdx.x;
    if (i < N) rowptr[i + 1] += bsum[i >> 8];
    if (i == 0) rowptr[0] = 0;
}

__global__ void scatter_kernel(const int* __restrict__ src, const int* __restrict__ dst,
                               const int* __restrict__ rowptr, int* __restrict__ cnt,
                               int* __restrict__ csrc, int E) {
    int i = blockIdx.x * blockDim.x + threadIdx.x;
    if (i < E) {
        int d = dst[i];
        int pos = rowptr[d] + atomicAdd(&cnt[d], 1);
        csrc[pos] = src[i];
    }
}

// ============================== casts / weight prep ==============================

__global__ void cast_bf16_4(const float* __restrict__ x, unsigned short* __restrict__ y, int n4) {
    int i = blockIdx.x * 256 + threadIdx.x;
    if (i < n4) {
        float4 v = reinterpret_cast<const float4*>(x)[i];
        ushort4 o;
        o.x = f2b(v.x); o.y = f2b(v.y); o.z = f2b(v.z); o.w = f2b(v.w);
        reinterpret_cast<ushort4*>(y)[i] = o;
    }
}

// W[K][Nin] (fp32) -> Wt[NBpad][K] (bf16), zero-pad rows >= Nin
__global__ void transW(const float* __restrict__ W, unsigned short* __restrict__ Wt,
                       int K, int Nin, int NBpad) {
    int idx = blockIdx.x * 256 + threadIdx.x;
    if (idx < NBpad * K) {
        int n = idx / K, k = idx % K;
        float v = (n < Nin) ? W[(size_t)k * Nin + n] : 0.f;
        Wt[idx] = f2b(v);
    }
}

// ============================== MFMA GEMM ==============================
// C[M,OUTW] = A[M,K](bf16) * Wt[NT*16,K](bf16)^T ; BM=128, 4 waves, wave=32 rows x NT*16 cols
template<int K, int NT, int OUTW, bool OBF16>
__global__ __launch_bounds__(256) void gemm_mfma(const unsigned short* __restrict__ A,
                                                 const unsigned short* __restrict__ Wt,
                                                 void* __restrict__ Cp, int M) {
    constexpr int BK = 64;
    constexpr int ST = 72;             // padded LDS stride (elems): 144 B = 36 dw -> 2-way
    constexpr int NB = NT * 16;
    __shared__ unsigned short lA[128 * ST];
    __shared__ unsigned short lB[NB * ST];
    const int tid = threadIdx.x;
    const int w = tid >> 6, l = tid & 63;
    const int lr = l & 15, lq = l >> 4;
    const int row0 = blockIdx.x * 128;
    f32x4 acc[2][NT] = {};

    for (int kc = 0; kc < K / BK; ++kc) {
        // stage A chunk: 128 rows x 128 B
        #pragma unroll
        for (int i = 0; i < 4; ++i) {
            int f = (i * 256 + tid) * 16;        // byte in compact chunk
            int row = f >> 7, cb = f & 127;
            int gr = row0 + row; if (gr >= M) gr = M - 1;
            float4 v = *reinterpret_cast<const float4*>(&A[(size_t)gr * K + kc * BK + (cb >> 1)]);
            *reinterpret_cast<float4*>(&lA[row * ST + (cb >> 1)]) = v;
        }
        // stage B chunk: NB rows x 128 B
        #pragma unroll
        for (int i = 0; i < (NB * 128 + 4095) / 4096; ++i) {
            int f = (i * 256 + tid) * 16;
            if (f < NB * 128) {
                int row = f >> 7, cb = f & 127;
                float4 v = *reinterpret_cast<const float4*>(&Wt[(size_t)row * K + kc * BK + (cb >> 1)]);
                *reinterpret_cast<float4*>(&lB[row * ST + (cb >> 1)]) = v;
            }
        }
        __syncthreads();
        #pragma unroll
        for (int ks = 0; ks < 2; ++ks) {
            const int kk = ks * 32 + lq * 8;
            bf16x8 aF[2], bF[NT];
            #pragma unroll
            for (int mr = 0; mr < 2; ++mr)
                aF[mr] = *reinterpret_cast<const bf16x8*>(&lA[(w * 32 + mr * 16 + lr) * ST + kk]);
            #pragma unroll
            for (int nr = 0; nr < NT; ++nr)
                bF[nr] = *reinterpret_cast<const bf16x8*>(&lB[(nr * 16 + lr) * ST + kk]);
            #pragma unroll
            for (int mr = 0; mr < 2; ++mr)
                #pragma unroll
                for (int nr = 0; nr < NT; ++nr)
                    acc[mr][nr] = __builtin_amdgcn_mfma_f32_16x16x32_bf16(aF[mr], bF[nr], acc[mr][nr], 0, 0, 0);
        }
        __syncthreads();
    }
    // epilogue: C/D layout col=l&15, row=(l>>4)*4+reg  [measured m89]
    #pragma unroll
    for (int mr = 0; mr < 2; ++mr) {
        int rbase = row0 + w * 32 + mr * 16 + lq * 4;
        #pragma unroll
        for (int reg = 0; reg < 4; ++reg) {
            int gr = rbase + reg;
            if (gr < M) {
                #pragma unroll
                for (int nr = 0; nr < NT; ++nr) {
                    int gc = nr * 16 + lr;
                    if (gc < OUTW) {
                        float v = acc[mr][nr][reg];
                        if (OBF16)
                            ((unsigned short*)Cp)[(size_t)gr * OUTW + gc] = f2b(v);
                        else
                            ((float*)Cp)[(size_t)gr * OUTW + gc] = v;
                    }
                }
            }
        }
    }
}

// ============================== el / er ==============================

// h:[N,128] bf16 (4 heads x 32), al/ar flat [128] fp32; wave per node
__global__ __launch_bounds__(256) void elr4(const unsigned short* __restrict__ h,
                                            const float* __restrict__ al,
                                            const float* __restrict__ ar,
                                            float* __restrict__ el, float* __restrict__ er, int N) {
    int wid = blockIdx.x * 4 + (threadIdx.x >> 6);
    int lane = threadIdx.x & 63;
    if (wid >= N) return;
    float h0 = b2f(h[(size_t)wid * 128 + lane]);
    float h1 = b2f(h[(size_t)wid * 128 + 64 + lane]);
    float pl0 = h0 * al[lane], pl1 = h1 * al[64 + lane];
    float pr0 = h0 * ar[lane], pr1 = h1 * ar[64 + lane];
    #pragma unroll
    for (int o = 16; o >= 1; o >>= 1) {
        pl0 += __shfl_xor(pl0, o); pl1 += __shfl_xor(pl1, o);
        pr0 += __shfl_xor(pr0, o); pr1 += __shfl_xor(pr1, o);
    }
    if ((lane & 31) == 0) {
        int hd = lane >> 5;
        el[wid * 4 + hd]     = pl0;
        el[wid * 4 + 2 + hd] = pl1;
        er[wid * 4 + hd]     = pr0;
        er[wid * 4 + 2 + hd] = pr1;
    }
}

// h:[N,40] fp32, al/ar [40]; wave per node
__global__ __launch_bounds__(256) void elr1(const float* __restrict__ h,
                                            const float* __restrict__ al,
                                            const float* __restrict__ ar,
                                            float* __restrict__ el, float* __restrict__ er, int N) {
    int wid = blockIdx.x * 4 + (threadIdx.x >> 6);
    int lane = threadIdx.x & 63;
    if (wid >= N) return;
    float hv = (lane < 40) ? h[(size_t)wid * 40 + lane] : 0.f;
    float pl = (lane < 40) ? hv * al[lane] : 0.f;
    float pr = (lane < 40) ? hv * ar[lane] : 0.f;
    #pragma unroll
    for (int o = 32; o >= 1; o >>= 1) { pl += __shfl_xor(pl, o); pr += __shfl_xor(pr, o); }
    if (lane == 0) { el[wid] = pl; er[wid] = pr; }
}

// ============================== aggregation ==============================

// 4-head GAT aggregation, one wave per dst node, online softmax, fused bias+relu
// h bf16 in, x bf16 out
template<bool RELU>
__global__ __launch_bounds__(256) void agg4(const unsigned short* __restrict__ h,
                                            const float* __restrict__ el,
                                            const float* __restrict__ er,
                                            const float* __restrict__ bias,
                                            const int* __restrict__ rowptr,
                                            const int* __restrict__ csrc,
                                            unsigned short* __restrict__ out, int N) {
    int wid = blockIdx.x * 4 + (threadIdx.x >> 6);
    int lane = threadIdx.x & 63;
    if (wid >= N) return;
    int beg = rowptr[wid], end = rowptr[wid + 1];
    int hA = lane >> 5;
    float erA = er[wid * 4 + hA];
    float erB = er[wid * 4 + 2 + hA];
    float mA = -INFINITY, mB = -INFINITY;
    float sA = 0.f, sB = 0.f, aA = 0.f, aB = 0.f;
    for (int p = beg; p < end; ++p) {
        int sid = csrc[p];
        float eA = el[sid * 4 + hA] + erA;     eA = eA > 0.f ? eA : 0.2f * eA;
        float eB = el[sid * 4 + 2 + hA] + erB; eB = eB > 0.f ? eB : 0.2f * eB;
        float hx0 = b2f(h[(size_t)sid * 128 + lane]);
        float hx1 = b2f(h[(size_t)sid * 128 + 64 + lane]);
        float nmA = fmaxf(mA, eA);
        float fA = __expf(mA - nmA);
        float pA = __expf(eA - nmA);
        sA = sA * fA + pA; aA = aA * fA + pA * hx0; mA = nmA;
        float nmB = fmaxf(mB, eB);
        float fB = __expf(mB - nmB);
        float pB = __expf(eB - nmB);
        sB = sB * fB + pB; aB = aB * fB + pB * hx1; mB = nmB;
    }
    float oA = (end > beg) ? aA / sA : 0.f;
    float oB = (end > beg) ? aB / sB : 0.f;
    oA += bias[lane];
    oB += bias[64 + lane];
    if (RELU) { oA = fmaxf(oA, 0.f); oB = fmaxf(oB, 0.f); }
    out[(size_t)wid * 128 + lane] = f2b(oA);
    out[(size_t)wid * 128 + 64 + lane] = f2b(oB);
}

// single-head aggregation + bias + log_softmax(40); h fp32, out fp32
__global__ __launch_bounds__(256) void agg1_lsm(const float* __restrict__ h,
                                                const float* __restrict__ el,
                                                const float* __restrict__ er,
                                                const float* __restrict__ bias,
                                                const int* __restrict__ rowptr,
                                                const int* __restrict__ csrc,
                                                float* __restrict__ out, int N) {
    int wid = blockIdx.x * 4 + (threadIdx.x >> 6);
    int lane = threadIdx.x & 63;
    if (wid >= N) return;
    int beg = rowptr[wid], end = rowptr[wid + 1];
    float ern = er[wid];
    float m = -INFINITY, s = 0.f, acc = 0.f;
    for (int p = beg; p < end; ++p) {
        int sid = csrc[p];
        float e = el[sid] + ern; e = e > 0.f ? e : 0.2f * e;
        float hx = (lane < 40) ? h[(size_t)sid * 40 + lane] : 0.f;
        float nm = fmaxf(m, e);
        float f = __expf(m - nm);
        float pe = __expf(e - nm);
        s = s * f + pe; acc = acc * f + pe * hx; m = nm;
    }
    float v = (end > beg) ? acc / s : 0.f;
    v += (lane < 40) ? bias[lane] : 0.f;
    float vv = (lane < 40) ? v : -INFINITY;
    float mx = vv;
    #pragma unroll
    for (int o = 32; o >= 1; o >>= 1) mx = fmaxf(mx, __shfl_xor(mx, o));
    float ex = (lane < 40) ? __expf(v - mx) : 0.f;
    float se = ex;
    #pragma unroll
    for (int o = 32; o >= 1; o >>= 1) se += __shfl_xor(se, o);
    if (lane < 40) out[(size_t)wid * 40 + lane] = v - mx - logf(se);
}

// ============================== launch ==============================

extern "C" void kernel_launch(void* const* d_in, const int* in_sizes, int n_in,
                              void* d_out, int out_size, void* d_ws, size_t ws_size,
                              hipStream_t stream) {
    const float* feat = (const float*)d_in[0];
    const float* W1  = (const float*)d_in[1];
    const float* al1 = (const float*)d_in[2];
    const float* ar1 = (const float*)d_in[3];
    const float* b1  = (const float*)d_in[4];
    const float* W2  = (const float*)d_in[5];
    const float* al2 = (const float*)d_in[6];
    const float* ar2 = (const float*)d_in[7];
    const float* b2  = (const float*)d_in[8];
    const float* W3  = (const float*)d_in[9];
    const float* al3 = (const float*)d_in[10];
    const float* ar3 = (const float*)d_in[11];
    const float* b3  = (const float*)d_in[12];
    const int*   src = (const int*)d_in[13];
    const int*   dst = (const int*)d_in[14];
    float* out = (float*)d_out;
    const int N = NN, E = NE;

    char* ws = (char*)d_ws;
    size_t off = 0;
    auto alloc = [&](size_t bytes) -> char* {
        char* p = ws + off;
        off += (bytes + 255) & ~(size_t)255;
        return p;
    };
    int*   deg    = (int*)alloc((size_t)N * 4);
    int*   rowptr = (int*)alloc((size_t)(N + 1) * 4);
    int*   bsum   = (int*)alloc(512 * 4);
    int*   csrc   = (int*)alloc((size_t)E * 4);
    float* el     = (float*)alloc((size_t)N * 4 * 4);
    float* er     = (float*)alloc((size_t)N * 4 * 4);
    unsigned short* featb = (unsigned short*)alloc((size_t)N * 256 * 2);  // also h3 (fp32 [N,40]) later
    unsigned short* hb    = (unsigned short*)alloc((size_t)N * 128 * 2);
    unsigned short* xb    = (unsigned short*)alloc((size_t)N * 128 * 2);
    unsigned short* W1t   = (unsigned short*)alloc((size_t)128 * 256 * 2);
    unsigned short* W2t   = (unsigned short*)alloc((size_t)128 * 128 * 2);
    unsigned short* W3t   = (unsigned short*)alloc((size_t)48 * 128 * 2);
    float* h3 = (float*)featb;  // reuse featb region after layer-1 GEMM (16 MB <= 51.2 MB)

    // ---- CSR build ----
    hipMemsetAsync(deg, 0, (size_t)N * 4, stream);
    hist_kernel<<<(E + 255) / 256, 256, 0, stream>>>(dst, deg, E);
    int NB = (N + 255) / 256;
    scan_local<<<NB, 256, 0, stream>>>(deg, rowptr, bsum, N);
    scan_bsum<<<1, 512, 0, stream>>>(bsum, NB);
    scan_add<<<(N + 255) / 256, 256, 0, stream>>>(rowptr, bsum, N);
    hipMemsetAsync(deg, 0, (size_t)N * 4, stream);
    scatter_kernel<<<(E + 255) / 256, 256, 0, stream>>>(src, dst, rowptr, deg, csrc, E);

    // ---- casts / weight prep ----
    int n4 = N * 256 / 4;
    cast_bf16_4<<<(n4 + 255) / 256, 256, 0, stream>>>(feat, featb, n4);
    transW<<<(128 * 256 + 255) / 256, 256, 0, stream>>>(W1, W1t, 256, 128, 128);
    transW<<<(128 * 128 + 255) / 256, 256, 0, stream>>>(W2, W2t, 128, 128, 128);
    transW<<<(48 * 128 + 255) / 256, 256, 0, stream>>>(W3, W3t, 128, 40, 48);

    int gemmGrid = (N + 127) / 128;
    int nodeGrid = (N + 3) / 4;

    // ---- layer 1 ----
    gemm_mfma<256, 8, 128, true><<<gemmGrid, 256, 0, stream>>>(featb, W1t, hb, N);
    elr4<<<nodeGrid, 256, 0, stream>>>(hb, al1, ar1, el, er, N);
    agg4<true><<<nodeGrid, 256, 0, stream>>>(hb, el, er, b1, rowptr, csrc, xb, N);

    // ---- layer 2 ----
    gemm_mfma<128, 8, 128, true><<<gemmGrid, 256, 0, stream>>>(xb, W2t, hb, N);
    elr4<<<nodeGrid, 256, 0, stream>>>(hb, al2, ar2, el, er, N);
    agg4<true><<<nodeGrid, 256, 0, stream>>>(hb, el, er, b2, rowptr, csrc, xb, N);

    // ---- layer 3 (+ fused log_softmax) ----
    gemm_mfma<128, 3, 40, false><<<gemmGrid, 256, 0, stream>>>(xb, W3t, h3, N);
    elr1<<<nodeGrid, 256, 0, stream>>>(h3, al3, ar3, el, er, N);
    agg1_lsm<<<nodeGrid, 256, 0, stream>>>(h3, el, er, b3, rowptr, csrc, out, N);
}

// Round 3
// 489.076 us; speedup vs baseline: 1.7835x; 1.2877x over previous
//
#include <hip/hip_runtime.h>
#include <hip/hip_bf16.h>
#include <math.h>

#define NN 100000
#define NE 1000000
#define CAP 128

typedef __attribute__((ext_vector_type(8))) short bf16x8;
typedef __attribute__((ext_vector_type(4))) float f32x4;
typedef unsigned int u32;
typedef unsigned short u16;

__device__ __forceinline__ u16 f2b(float f) {
    __hip_bfloat16 h = __float2bfloat16(f);
    return *reinterpret_cast<u16*>(&h);
}
__device__ __forceinline__ float b2f(u16 u) {
    __hip_bfloat16 h = *reinterpret_cast<__hip_bfloat16*>(&u);
    return __bfloat162float(h);
}
__device__ __forceinline__ float bflo(u32 v) { return __uint_as_float(v << 16); }
__device__ __forceinline__ float bfhi(u32 v) { return __uint_as_float(v & 0xffff0000u); }

// ============================== CSR build ==============================

__global__ void hist_kernel(const int* __restrict__ dst, int* __restrict__ deg, int E) {
    int i = blockIdx.x * blockDim.x + threadIdx.x;
    if (i < E) atomicAdd(&deg[dst[i]], 1);
}

__global__ void scan_local(const int* __restrict__ deg, int* __restrict__ rowptr,
                           int* __restrict__ bsum, int N) {
    __shared__ int s[256];
    int i = blockIdx.x * 256 + threadIdx.x;
    int v = (i < N) ? deg[i] : 0;
    s[threadIdx.x] = v;
    __syncthreads();
    #pragma unroll
    for (int off = 1; off < 256; off <<= 1) {
        int t = (threadIdx.x >= off) ? s[threadIdx.x - off] : 0;
        __syncthreads();
        s[threadIdx.x] += t;
        __syncthreads();
    }
    if (i < N) rowptr[i + 1] = s[threadIdx.x];
    if (threadIdx.x == 255) bsum[blockIdx.x] = s[255];
}

__global__ void scan_bsum(int* __restrict__ bsum, int NB) {
    __shared__ int s[512];
    int v = (threadIdx.x < NB) ? bsum[threadIdx.x] : 0;
    s[threadIdx.x] = v;
    __syncthreads();
    for (int off = 1; off < 512; off <<= 1) {
        int t = (threadIdx.x >= off) ? s[threadIdx.x - off] : 0;
        __syncthreads();
        s[threadIdx.x] += t;
        __syncthreads();
    }
    if (threadIdx.x < NB) bsum[threadIdx.x] = s[threadIdx.x] - v;  // exclusive
}

__global__ void scan_add(int* __restrict__ rowptr, const int* __restrict__ bsum, int N) {
    int i = blockIdx.x * blockDim.x + threadIdx.x;
    if (i < N) rowptr[i + 1] += bsum[i >> 8];
    if (i == 0) rowptr[0] = 0;
}

__global__ void scatter_kernel(const int* __restrict__ src, const int* __restrict__ dst,
                               const int* __restrict__ rowptr, int* __restrict__ cnt,
                               int* __restrict__ csrc, int E) {
    int i = blockIdx.x * blockDim.x + threadIdx.x;
    if (i < E) {
        int d = dst[i];
        int pos = rowptr[d] + atomicAdd(&cnt[d], 1);
        csrc[pos] = src[i];
    }
}

// ============================== weight prep ==============================

// W[K][Nin] (fp32) -> Wt[NBpad][K] (bf16), zero-pad rows >= Nin
__global__ void transW(const float* __restrict__ W, u16* __restrict__ Wt,
                       int K, int Nin, int NBpad) {
    int idx = blockIdx.x * 256 + threadIdx.x;
    if (idx < NBpad * K) {
        int n = idx / K, k = idx % K;
        float v = (n < Nin) ? W[(size_t)k * Nin + n] : 0.f;
        Wt[idx] = f2b(v);
    }
}

// ============================== MFMA GEMM ==============================
// C[M,OUTW] = A[M,K] * Wt[NT*16,K]^T ; BM=128, 4 waves, wave=32 rows x NT*16 cols
// AF32: A is fp32, cast fused into staging. OBF16: output bf16.
template<int K, int NT, int OUTW, bool OBF16, bool AF32>
__global__ __launch_bounds__(256) void gemm_mfma(const void* __restrict__ Ap_,
                                                 const u16* __restrict__ Wt,
                                                 void* __restrict__ Cp, int M) {
    constexpr int BK = 64;
    constexpr int ST = 72;             // padded LDS stride (elems): 144 B -> 2-way (free)
    constexpr int NB = NT * 16;
    __shared__ u16 lA[128 * ST];
    __shared__ u16 lB[NB * ST];
    const int tid = threadIdx.x;
    const int w = tid >> 6, l = tid & 63;
    const int lr = l & 15, lq = l >> 4;
    const int row0 = blockIdx.x * 128;
    f32x4 acc[2][NT] = {};
    const u16* Ab = (const u16*)Ap_;
    const float* Af = (const float*)Ap_;

    for (int kc = 0; kc < K / BK; ++kc) {
        // stage A chunk: 128 rows x 64 elems (bf16)
        #pragma unroll
        for (int i = 0; i < 4; ++i) {
            int f = (i * 256 + tid) * 16;        // byte in compact bf16 chunk
            int row = f >> 7, cb = f & 127;
            int ce = cb >> 1;
            int gr = row0 + row; if (gr >= M) gr = M - 1;
            if (AF32) {
                const float* s = &Af[(size_t)gr * K + kc * BK + ce];
                float4 v0 = *reinterpret_cast<const float4*>(s);
                float4 v1 = *reinterpret_cast<const float4*>(s + 4);
                ushort4 t0, t1;
                t0.x = f2b(v0.x); t0.y = f2b(v0.y); t0.z = f2b(v0.z); t0.w = f2b(v0.w);
                t1.x = f2b(v1.x); t1.y = f2b(v1.y); t1.z = f2b(v1.z); t1.w = f2b(v1.w);
                *reinterpret_cast<ushort4*>(&lA[row * ST + ce]) = t0;
                *reinterpret_cast<ushort4*>(&lA[row * ST + ce + 4]) = t1;
            } else {
                float4 v = *reinterpret_cast<const float4*>(&Ab[(size_t)gr * K + kc * BK + ce]);
                *reinterpret_cast<float4*>(&lA[row * ST + ce]) = v;
            }
        }
        // stage B chunk: NB rows x 64 elems
        #pragma unroll
        for (int i = 0; i < (NB * 128 + 4095) / 4096; ++i) {
            int f = (i * 256 + tid) * 16;
            if (f < NB * 128) {
                int row = f >> 7, ce = (f & 127) >> 1;
                float4 v = *reinterpret_cast<const float4*>(&Wt[(size_t)row * K + kc * BK + ce]);
                *reinterpret_cast<float4*>(&lB[row * ST + ce]) = v;
            }
        }
        __syncthreads();
        #pragma unroll
        for (int ks = 0; ks < 2; ++ks) {
            const int kk = ks * 32 + lq * 8;
            bf16x8 aF[2], bF[NT];
            #pragma unroll
            for (int mr = 0; mr < 2; ++mr)
                aF[mr] = *reinterpret_cast<const bf16x8*>(&lA[(w * 32 + mr * 16 + lr) * ST + kk]);
            #pragma unroll
            for (int nr = 0; nr < NT; ++nr)
                bF[nr] = *reinterpret_cast<const bf16x8*>(&lB[(nr * 16 + lr) * ST + kk]);
            #pragma unroll
            for (int mr = 0; mr < 2; ++mr)
                #pragma unroll
                for (int nr = 0; nr < NT; ++nr)
                    acc[mr][nr] = __builtin_amdgcn_mfma_f32_16x16x32_bf16(aF[mr], bF[nr], acc[mr][nr], 0, 0, 0);
        }
        __syncthreads();
    }
    // epilogue: C/D layout col=l&15, row=(l>>4)*4+reg  [measured m89]
    #pragma unroll
    for (int mr = 0; mr < 2; ++mr) {
        int rbase = row0 + w * 32 + mr * 16 + lq * 4;
        #pragma unroll
        for (int reg = 0; reg < 4; ++reg) {
            int gr = rbase + reg;
            if (gr < M) {
                #pragma unroll
                for (int nr = 0; nr < NT; ++nr) {
                    int gc = nr * 16 + lr;
                    if (gc < OUTW) {
                        float v = acc[mr][nr][reg];
                        if (OBF16)
                            ((u16*)Cp)[(size_t)gr * OUTW + gc] = f2b(v);
                        else
                            ((float*)Cp)[(size_t)gr * OUTW + gc] = v;
                    }
                }
            }
        }
    }
}

// ============================== el / er ==============================

// h:[N,128] bf16 (4 heads x 32), al/ar flat [128] fp32; wave per node
__global__ __launch_bounds__(256) void elr4(const u16* __restrict__ h,
                                            const float* __restrict__ al,
                                            const float* __restrict__ ar,
                                            float* __restrict__ el, float* __restrict__ er, int N) {
    int wid = blockIdx.x * 4 + (threadIdx.x >> 6);
    int lane = threadIdx.x & 63;
    if (wid >= N) return;
    float h0 = b2f(h[(size_t)wid * 128 + lane]);
    float h1 = b2f(h[(size_t)wid * 128 + 64 + lane]);
    float pl0 = h0 * al[lane], pl1 = h1 * al[64 + lane];
    float pr0 = h0 * ar[lane], pr1 = h1 * ar[64 + lane];
    #pragma unroll
    for (int o = 16; o >= 1; o >>= 1) {
        pl0 += __shfl_xor(pl0, o); pl1 += __shfl_xor(pl1, o);
        pr0 += __shfl_xor(pr0, o); pr1 += __shfl_xor(pr1, o);
    }
    if ((lane & 31) == 0) {
        int hd = lane >> 5;
        el[wid * 4 + hd]     = pl0;
        el[wid * 4 + 2 + hd] = pl1;
        er[wid * 4 + hd]     = pr0;
        er[wid * 4 + 2 + hd] = pr1;
    }
}

// h:[N,40] bf16, al/ar [40]; wave per node
__global__ __launch_bounds__(256) void elr1(const u16* __restrict__ h,
                                            const float* __restrict__ al,
                                            const float* __restrict__ ar,
                                            float* __restrict__ el, float* __restrict__ er, int N) {
    int wid = blockIdx.x * 4 + (threadIdx.x >> 6);
    int lane = threadIdx.x & 63;
    if (wid >= N) return;
    float hv = (lane < 40) ? b2f(h[(size_t)wid * 40 + lane]) : 0.f;
    float pl = (lane < 40) ? hv * al[lane] : 0.f;
    float pr = (lane < 40) ? hv * ar[lane] : 0.f;
    #pragma unroll
    for (int o = 32; o >= 1; o >>= 1) { pl += __shfl_xor(pl, o); pr += __shfl_xor(pr, o); }
    if (lane == 0) { el[wid] = pl; er[wid] = pr; }
}

// ============================== aggregation (two-phase) ==============================

// 4-head GAT aggregation, wave per dst node.
// Phase 1 (edge-parallel): e -> LDS, butterfly max/sum. Phase 2 (feature-parallel): stream fma.
template<bool RELU>
__global__ __launch_bounds__(256) void agg4v2(const u32* __restrict__ h,   // [N][64] dwords = 128 bf16
                                              const float4* __restrict__ el4,
                                              const float4* __restrict__ er4,
                                              const float* __restrict__ bias,
                                              const int* __restrict__ rowptr,
                                              const int* __restrict__ csrc,
                                              u32* __restrict__ out, int N) {
    __shared__ float4 s_ew[4][CAP];
    __shared__ int s_sid[4][CAP];
    const int wslot = threadIdx.x >> 6, lane = threadIdx.x & 63;
    const int wid = blockIdx.x * 4 + wslot;
    if (wid >= N) return;
    const int beg = rowptr[wid];
    const int deg = rowptr[wid + 1] - beg;
    const float4 er = er4[wid];
    const int hh = lane >> 4;                       // head of features 2*lane, 2*lane+1
    const float2 bv = reinterpret_cast<const float2*>(bias)[lane];
    float accA = 0.f, accB = 0.f, invs;

    if (deg <= CAP) {
        float m0 = -INFINITY, m1 = -INFINITY, m2 = -INFINITY, m3 = -INFINITY;
        for (int base = 0; base < deg; base += 64) {
            int j = base + lane;
            if (j < deg) {
                int sid = csrc[beg + j];
                float4 ev = el4[sid];
                float e0 = ev.x + er.x; e0 = e0 > 0.f ? e0 : 0.2f * e0;
                float e1 = ev.y + er.y; e1 = e1 > 0.f ? e1 : 0.2f * e1;
                float e2 = ev.z + er.z; e2 = e2 > 0.f ? e2 : 0.2f * e2;
                float e3 = ev.w + er.w; e3 = e3 > 0.f ? e3 : 0.2f * e3;
                s_sid[wslot][j] = sid;
                s_ew[wslot][j] = make_float4(e0, e1, e2, e3);
                m0 = fmaxf(m0, e0); m1 = fmaxf(m1, e1);
                m2 = fmaxf(m2, e2); m3 = fmaxf(m3, e3);
            }
        }
        #pragma unroll
        for (int o = 32; o >= 1; o >>= 1) {
            m0 = fmaxf(m0, __shfl_xor(m0, o)); m1 = fmaxf(m1, __shfl_xor(m1, o));
            m2 = fmaxf(m2, __shfl_xor(m2, o)); m3 = fmaxf(m3, __shfl_xor(m3, o));
        }
        float s0 = 0.f, s1 = 0.f, s2 = 0.f, s3 = 0.f;
        for (int base = 0; base < deg; base += 64) {
            int j = base + lane;
            if (j < deg) {
                float4 ev = s_ew[wslot][j];
                float p0 = __expf(ev.x - m0), p1 = __expf(ev.y - m1);
                float p2 = __expf(ev.z - m2), p3 = __expf(ev.w - m3);
                s_ew[wslot][j] = make_float4(p0, p1, p2, p3);
                s0 += p0; s1 += p1; s2 += p2; s3 += p3;
            }
        }
        #pragma unroll
        for (int o = 32; o >= 1; o >>= 1) {
            s0 += __shfl_xor(s0, o); s1 += __shfl_xor(s1, o);
            s2 += __shfl_xor(s2, o); s3 += __shfl_xor(s3, o);
        }
        float sh = hh == 0 ? s0 : hh == 1 ? s1 : hh == 2 ? s2 : s3;
        invs = (deg > 0) ? 1.f / sh : 0.f;
        const float* ewf = reinterpret_cast<const float*>(&s_ew[wslot][0]);
        #pragma unroll 2
        for (int j = 0; j < deg; ++j) {
            int sid = s_sid[wslot][j];
            float wgt = ewf[j * 4 + hh];
            u32 hv = h[(size_t)sid * 64 + lane];
            accA = fmaf(wgt, bflo(hv), accA);
            accB = fmaf(wgt, bfhi(hv), accB);
        }
    } else {
        // streaming fallback (never expected for this input; keeps correctness general)
        float er_h = hh == 0 ? er.x : hh == 1 ? er.y : hh == 2 ? er.z : er.w;
        float m = -INFINITY, s = 0.f;
        for (int p = beg; p < beg + deg; ++p) {
            int sid = csrc[p];
            float4 ev = el4[sid];
            float e = (hh == 0 ? ev.x : hh == 1 ? ev.y : hh == 2 ? ev.z : ev.w) + er_h;
            e = e > 0.f ? e : 0.2f * e;
            float nm = fmaxf(m, e);
            float f = __expf(m - nm), pe = __expf(e - nm);
            u32 hv = h[(size_t)sid * 64 + lane];
            s = s * f + pe;
            accA = accA * f + pe * bflo(hv);
            accB = accB * f + pe * bfhi(hv);
            m = nm;
        }
        invs = 1.f / s;
    }
    float oA = accA * invs + bv.x;
    float oB = accB * invs + bv.y;
    if (RELU) { oA = fmaxf(oA, 0.f); oB = fmaxf(oB, 0.f); }
    out[(size_t)wid * 64 + lane] = ((u32)f2b(oB) << 16) | (u32)f2b(oA);
}

// single-head aggregation + bias + log_softmax(40); h [N,40] bf16, out fp32
__global__ __launch_bounds__(256) void agg1v2(const u16* __restrict__ h,
                                              const float* __restrict__ el,
                                              const float* __restrict__ er,
                                              const float* __restrict__ bias,
                                              const int* __restrict__ rowptr,
                                              const int* __restrict__ csrc,
                                              float* __restrict__ out, int N) {
    __shared__ float s_ew[4][CAP];
    __shared__ int s_sid[4][CAP];
    const int wslot = threadIdx.x >> 6, lane = threadIdx.x & 63;
    const int wid = blockIdx.x * 4 + wslot;
    if (wid >= N) return;
    const int beg = rowptr[wid];
    const int deg = rowptr[wid + 1] - beg;
    const float ern = er[wid];
    float acc = 0.f, invs;

    if (deg <= CAP) {
        float m = -INFINITY;
        for (int base = 0; base < deg; base += 64) {
            int j = base + lane;
            if (j < deg) {
                int sid = csrc[beg + j];
                float e = el[sid] + ern; e = e > 0.f ? e : 0.2f * e;
                s_sid[wslot][j] = sid;
                s_ew[wslot][j] = e;
                m = fmaxf(m, e);
            }
        }
        #pragma unroll
        for (int o = 32; o >= 1; o >>= 1) m = fmaxf(m, __shfl_xor(m, o));
        float s = 0.f;
        for (int base = 0; base < deg; base += 64) {
            int j = base + lane;
            if (j < deg) {
                float p = __expf(s_ew[wslot][j] - m);
                s_ew[wslot][j] = p;
                s += p;
            }
        }
        #pragma unroll
        for (int o = 32; o >= 1; o >>= 1) s += __shfl_xor(s, o);
        invs = (deg > 0) ? 1.f / s : 0.f;
        #pragma unroll 2
        for (int j = 0; j < deg; ++j) {
            int sid = s_sid[wslot][j];
            float wgt = s_ew[wslot][j];
            if (lane < 40) acc = fmaf(wgt, b2f(h[(size_t)sid * 40 + lane]), acc);
        }
    } else {
        float m = -INFINITY, s = 0.f;
        for (int p = beg; p < beg + deg; ++p) {
            int sid = csrc[p];
            float e = el[sid] + ern; e = e > 0.f ? e : 0.2f * e;
            float nm = fmaxf(m, e);
            float f = __expf(m - nm), pe = __expf(e - nm);
            float hx = (lane < 40) ? b2f(h[(size_t)sid * 40 + lane]) : 0.f;
            s = s * f + pe;
            acc = acc * f + pe * hx;
            m = nm;
        }
        invs = 1.f / s;
    }
    float v = acc * invs + ((lane < 40) ? bias[lane] : 0.f);
    float vv = (lane < 40) ? v : -INFINITY;
    float mx = vv;
    #pragma unroll
    for (int o = 32; o >= 1; o >>= 1) mx = fmaxf(mx, __shfl_xor(mx, o));
    float ex = (lane < 40) ? __expf(v - mx) : 0.f;
    float se = ex;
    #pragma unroll
    for (int o = 32; o >= 1; o >>= 1) se += __shfl_xor(se, o);
    if (lane < 40) out[(size_t)wid * 40 + lane] = v - mx - logf(se);
}

// ============================== launch ==============================

extern "C" void kernel_launch(void* const* d_in, const int* in_sizes, int n_in,
                              void* d_out, int out_size, void* d_ws, size_t ws_size,
                              hipStream_t stream) {
    const float* feat = (const float*)d_in[0];
    const float* W1  = (const float*)d_in[1];
    const float* al1 = (const float*)d_in[2];
    const float* ar1 = (const float*)d_in[3];
    const float* b1  = (const float*)d_in[4];
    const float* W2  = (const float*)d_in[5];
    const float* al2 = (const float*)d_in[6];
    const float* ar2 = (const float*)d_in[7];
    const float* b2  = (const float*)d_in[8];
    const float* W3  = (const float*)d_in[9];
    const float* al3 = (const float*)d_in[10];
    const float* ar3 = (const float*)d_in[11];
    const float* b3  = (const float*)d_in[12];
    const int*   src = (const int*)d_in[13];
    const int*   dst = (const int*)d_in[14];
    float* out = (float*)d_out;
    const int N = NN, E = NE;

    char* ws = (char*)d_ws;
    size_t off = 0;
    auto alloc = [&](size_t bytes) -> char* {
        char* p = ws + off;
        off += (bytes + 255) & ~(size_t)255;
        return p;
    };
    int* deg    = (int*)alloc((size_t)N * 4);
    int* rowptr = (int*)alloc((size_t)(N + 1) * 4);
    int* bsum   = (int*)alloc(512 * 4);
    int* csrc   = (int*)alloc((size_t)E * 4);
    float* el   = (float*)alloc((size_t)N * 4 * 4);
    float* er   = (float*)alloc((size_t)N * 4 * 4);
    u16* hb     = (u16*)alloc((size_t)N * 128 * 2);
    u16* xb     = (u16*)alloc((size_t)N * 128 * 2);
    u16* h3     = (u16*)alloc((size_t)N * 40 * 2);
    u16* W1t    = (u16*)alloc((size_t)128 * 256 * 2);
    u16* W2t    = (u16*)alloc((size_t)128 * 128 * 2);
    u16* W3t    = (u16*)alloc((size_t)48 * 128 * 2);

    // ---- CSR build ----
    hipMemsetAsync(deg, 0, (size_t)N * 4, stream);
    hist_kernel<<<(E + 255) / 256, 256, 0, stream>>>(dst, deg, E);
    int NB = (N + 255) / 256;
    scan_local<<<NB, 256, 0, stream>>>(deg, rowptr, bsum, N);
    scan_bsum<<<1, 512, 0, stream>>>(bsum, NB);
    scan_add<<<(N + 255) / 256, 256, 0, stream>>>(rowptr, bsum, N);
    hipMemsetAsync(deg, 0, (size_t)N * 4, stream);
    scatter_kernel<<<(E + 255) / 256, 256, 0, stream>>>(src, dst, rowptr, deg, csrc, E);

    // ---- weight prep ----
    transW<<<(128 * 256 + 255) / 256, 256, 0, stream>>>(W1, W1t, 256, 128, 128);
    transW<<<(128 * 128 + 255) / 256, 256, 0, stream>>>(W2, W2t, 128, 128, 128);
    transW<<<(48 * 128 + 255) / 256, 256, 0, stream>>>(W3, W3t, 128, 40, 48);

    int gemmGrid = (N + 127) / 128;
    int nodeGrid = (N + 3) / 4;

    // ---- layer 1 (cast fused into GEMM A-staging) ----
    gemm_mfma<256, 8, 128, true, true><<<gemmGrid, 256, 0, stream>>>(feat, W1t, hb, N);
    elr4<<<nodeGrid, 256, 0, stream>>>(hb, al1, ar1, el, er, N);
    agg4v2<true><<<nodeGrid, 256, 0, stream>>>((const u32*)hb, (const float4*)el, (const float4*)er,
                                               b1, rowptr, csrc, (u32*)xb, N);

    // ---- layer 2 ----
    gemm_mfma<128, 8, 128, true, false><<<gemmGrid, 256, 0, stream>>>(xb, W2t, hb, N);
    elr4<<<nodeGrid, 256, 0, stream>>>(hb, al2, ar2, el, er, N);
    agg4v2<true><<<nodeGrid, 256, 0, stream>>>((const u32*)hb, (const float4*)el, (const float4*)er,
                                               b2, rowptr, csrc, (u32*)xb, N);

    // ---- layer 3 (+ fused log_softmax) ----
    gemm_mfma<128, 3, 40, true, false><<<gemmGrid, 256, 0, stream>>>(xb, W3t, h3, N);
    elr1<<<nodeGrid, 256, 0, stream>>>(h3, al3, ar3, el, er, N);
    agg1v2<<<nodeGrid, 256, 0, stream>>>(h3, el, er, b3, rowptr, csrc, out, N);
}

// Round 4
// 438.553 us; speedup vs baseline: 1.9890x; 1.1152x over previous
//
#include <hip/hip_runtime.h>
#include <hip/hip_bf16.h>
#include <math.h>

#define NN 100000
#define NE 1000000
#define CAP 128

typedef __attribute__((ext_vector_type(8))) short bf16x8;
typedef __attribute__((ext_vector_type(4))) float f32x4;
typedef unsigned int u32;
typedef unsigned short u16;

__device__ __forceinline__ u16 f2b(float f) {
    __hip_bfloat16 h = __float2bfloat16(f);
    return *reinterpret_cast<u16*>(&h);
}
__device__ __forceinline__ float b2f(u16 u) {
    __hip_bfloat16 h = *reinterpret_cast<__hip_bfloat16*>(&u);
    return __bfloat162float(h);
}
__device__ __forceinline__ float bflo(u32 v) { return __uint_as_float(v << 16); }
__device__ __forceinline__ float bfhi(u32 v) { return __uint_as_float(v & 0xffff0000u); }

// ============================== CSR build ==============================

__global__ void hist_kernel(const int* __restrict__ dst, int* __restrict__ deg, int E) {
    int i = blockIdx.x * blockDim.x + threadIdx.x;
    if (i < E) atomicAdd(&deg[dst[i]], 1);
}

__global__ void scan_local(const int* __restrict__ deg, int* __restrict__ rowptr,
                           int* __restrict__ bsum, int N) {
    __shared__ int s[256];
    int i = blockIdx.x * 256 + threadIdx.x;
    int v = (i < N) ? deg[i] : 0;
    s[threadIdx.x] = v;
    __syncthreads();
    #pragma unroll
    for (int off = 1; off < 256; off <<= 1) {
        int t = (threadIdx.x >= off) ? s[threadIdx.x - off] : 0;
        __syncthreads();
        s[threadIdx.x] += t;
        __syncthreads();
    }
    if (i < N) rowptr[i + 1] = s[threadIdx.x];
    if (threadIdx.x == 255) bsum[blockIdx.x] = s[255];
}

__global__ void scan_bsum(int* __restrict__ bsum, int NB) {
    __shared__ int s[512];
    int v = (threadIdx.x < NB) ? bsum[threadIdx.x] : 0;
    s[threadIdx.x] = v;
    __syncthreads();
    for (int off = 1; off < 512; off <<= 1) {
        int t = (threadIdx.x >= off) ? s[threadIdx.x - off] : 0;
        __syncthreads();
        s[threadIdx.x] += t;
        __syncthreads();
    }
    if (threadIdx.x < NB) bsum[threadIdx.x] = s[threadIdx.x] - v;  // exclusive
}

__global__ void scan_add(int* __restrict__ rowptr, const int* __restrict__ bsum, int N) {
    int i = blockIdx.x * blockDim.x + threadIdx.x;
    if (i < N) rowptr[i + 1] += bsum[i >> 8];
    if (i == 0) rowptr[0] = 0;
}

__global__ void scatter_kernel(const int* __restrict__ src, const int* __restrict__ dst,
                               const int* __restrict__ rowptr, int* __restrict__ cnt,
                               int* __restrict__ csrc, int E) {
    int i = blockIdx.x * blockDim.x + threadIdx.x;
    if (i < E) {
        int d = dst[i];
        int pos = rowptr[d] + atomicAdd(&cnt[d], 1);
        csrc[pos] = src[i];
    }
}

// ============================== weight prep ==============================

__global__ void transW(const float* __restrict__ W, u16* __restrict__ Wt,
                       int K, int Nin, int NBpad) {
    int idx = blockIdx.x * 256 + threadIdx.x;
    if (idx < NBpad * K) {
        int n = idx / K, k = idx % K;
        float v = (n < Nin) ? W[(size_t)k * Nin + n] : 0.f;
        Wt[idx] = f2b(v);
    }
}

// ============================== MFMA GEMM ==============================
template<int K, int NT, int OUTW, bool OBF16, bool AF32>
__global__ __launch_bounds__(256) void gemm_mfma(const void* __restrict__ Ap_,
                                                 const u16* __restrict__ Wt,
                                                 void* __restrict__ Cp, int M) {
    constexpr int BK = 64;
    constexpr int ST = 72;
    constexpr int NB = NT * 16;
    __shared__ u16 lA[128 * ST];
    __shared__ u16 lB[NB * ST];
    const int tid = threadIdx.x;
    const int w = tid >> 6, l = tid & 63;
    const int lr = l & 15, lq = l >> 4;
    const int row0 = blockIdx.x * 128;
    f32x4 acc[2][NT] = {};
    const u16* Ab = (const u16*)Ap_;
    const float* Af = (const float*)Ap_;

    for (int kc = 0; kc < K / BK; ++kc) {
        #pragma unroll
        for (int i = 0; i < 4; ++i) {
            int f = (i * 256 + tid) * 16;
            int row = f >> 7, cb = f & 127;
            int ce = cb >> 1;
            int gr = row0 + row; if (gr >= M) gr = M - 1;
            if (AF32) {
                const float* s = &Af[(size_t)gr * K + kc * BK + ce];
                float4 v0 = *reinterpret_cast<const float4*>(s);
                float4 v1 = *reinterpret_cast<const float4*>(s + 4);
                ushort4 t0, t1;
                t0.x = f2b(v0.x); t0.y = f2b(v0.y); t0.z = f2b(v0.z); t0.w = f2b(v0.w);
                t1.x = f2b(v1.x); t1.y = f2b(v1.y); t1.z = f2b(v1.z); t1.w = f2b(v1.w);
                *reinterpret_cast<ushort4*>(&lA[row * ST + ce]) = t0;
                *reinterpret_cast<ushort4*>(&lA[row * ST + ce + 4]) = t1;
            } else {
                float4 v = *reinterpret_cast<const float4*>(&Ab[(size_t)gr * K + kc * BK + ce]);
                *reinterpret_cast<float4*>(&lA[row * ST + ce]) = v;
            }
        }
        #pragma unroll
        for (int i = 0; i < (NB * 128 + 4095) / 4096; ++i) {
            int f = (i * 256 + tid) * 16;
            if (f < NB * 128) {
                int row = f >> 7, ce = (f & 127) >> 1;
                float4 v = *reinterpret_cast<const float4*>(&Wt[(size_t)row * K + kc * BK + ce]);
                *reinterpret_cast<float4*>(&lB[row * ST + ce]) = v;
            }
        }
        __syncthreads();
        #pragma unroll
        for (int ks = 0; ks < 2; ++ks) {
            const int kk = ks * 32 + lq * 8;
            bf16x8 aF[2], bF[NT];
            #pragma unroll
            for (int mr = 0; mr < 2; ++mr)
                aF[mr] = *reinterpret_cast<const bf16x8*>(&lA[(w * 32 + mr * 16 + lr) * ST + kk]);
            #pragma unroll
            for (int nr = 0; nr < NT; ++nr)
                bF[nr] = *reinterpret_cast<const bf16x8*>(&lB[(nr * 16 + lr) * ST + kk]);
            #pragma unroll
            for (int mr = 0; mr < 2; ++mr)
                #pragma unroll
                for (int nr = 0; nr < NT; ++nr)
                    acc[mr][nr] = __builtin_amdgcn_mfma_f32_16x16x32_bf16(aF[mr], bF[nr], acc[mr][nr], 0, 0, 0);
        }
        __syncthreads();
    }
    #pragma unroll
    for (int mr = 0; mr < 2; ++mr) {
        int rbase = row0 + w * 32 + mr * 16 + lq * 4;
        #pragma unroll
        for (int reg = 0; reg < 4; ++reg) {
            int gr = rbase + reg;
            if (gr < M) {
                #pragma unroll
                for (int nr = 0; nr < NT; ++nr) {
                    int gc = nr * 16 + lr;
                    if (gc < OUTW) {
                        float v = acc[mr][nr][reg];
                        if (OBF16)
                            ((u16*)Cp)[(size_t)gr * OUTW + gc] = f2b(v);
                        else
                            ((float*)Cp)[(size_t)gr * OUTW + gc] = v;
                    }
                }
            }
        }
    }
}

// ============================== el / er ==============================

__global__ __launch_bounds__(256) void elr4(const u16* __restrict__ h,
                                            const float* __restrict__ al,
                                            const float* __restrict__ ar,
                                            float* __restrict__ el, float* __restrict__ er, int N) {
    int wid = blockIdx.x * 4 + (threadIdx.x >> 6);
    int lane = threadIdx.x & 63;
    if (wid >= N) return;
    float h0 = b2f(h[(size_t)wid * 128 + lane]);
    float h1 = b2f(h[(size_t)wid * 128 + 64 + lane]);
    float pl0 = h0 * al[lane], pl1 = h1 * al[64 + lane];
    float pr0 = h0 * ar[lane], pr1 = h1 * ar[64 + lane];
    #pragma unroll
    for (int o = 16; o >= 1; o >>= 1) {
        pl0 += __shfl_xor(pl0, o); pl1 += __shfl_xor(pl1, o);
        pr0 += __shfl_xor(pr0, o); pr1 += __shfl_xor(pr1, o);
    }
    if ((lane & 31) == 0) {
        int hd = lane >> 5;
        el[wid * 4 + hd]     = pl0;
        el[wid * 4 + 2 + hd] = pl1;
        er[wid * 4 + hd]     = pr0;
        er[wid * 4 + 2 + hd] = pr1;
    }
}

__global__ __launch_bounds__(256) void elr1(const u16* __restrict__ h,
                                            const float* __restrict__ al,
                                            const float* __restrict__ ar,
                                            float* __restrict__ el, float* __restrict__ er, int N) {
    int wid = blockIdx.x * 4 + (threadIdx.x >> 6);
    int lane = threadIdx.x & 63;
    if (wid >= N) return;
    float hv = (lane < 40) ? b2f(h[(size_t)wid * 40 + lane]) : 0.f;
    float pl = (lane < 40) ? hv * al[lane] : 0.f;
    float pr = (lane < 40) ? hv * ar[lane] : 0.f;
    #pragma unroll
    for (int o = 32; o >= 1; o >>= 1) { pl += __shfl_xor(pl, o); pr += __shfl_xor(pr, o); }
    if (lane == 0) { el[wid] = pl; er[wid] = pr; }
}

// ============================== aggregation (two-phase + 4-edge ILP) ==============================

template<bool RELU>
__global__ __launch_bounds__(256) void agg4v2(const u32* __restrict__ h,   // [N][64] dwords
                                              const float4* __restrict__ el4,
                                              const float4* __restrict__ er4,
                                              const float* __restrict__ bias,
                                              const int* __restrict__ rowptr,
                                              const int* __restrict__ csrc,
                                              u32* __restrict__ out, int N) {
    __shared__ float4 s_ew[4][CAP];
    __shared__ int s_sid[4][CAP];
    const int wslot = threadIdx.x >> 6, lane = threadIdx.x & 63;
    const int wid = blockIdx.x * 4 + wslot;
    if (wid >= N) return;
    const int beg = rowptr[wid];
    const int deg = rowptr[wid + 1] - beg;
    const float4 er = er4[wid];
    const int hh = lane >> 4;
    const float2 bv = reinterpret_cast<const float2*>(bias)[lane];
    float accA = 0.f, accB = 0.f, invs;

    if (deg <= CAP) {
        float m0 = -INFINITY, m1 = -INFINITY, m2 = -INFINITY, m3 = -INFINITY;
        for (int base = 0; base < deg; base += 64) {
            int j = base + lane;
            if (j < deg) {
                int sid = csrc[beg + j];
                float4 ev = el4[sid];
                float e0 = ev.x + er.x; e0 = e0 > 0.f ? e0 : 0.2f * e0;
                float e1 = ev.y + er.y; e1 = e1 > 0.f ? e1 : 0.2f * e1;
                float e2 = ev.z + er.z; e2 = e2 > 0.f ? e2 : 0.2f * e2;
                float e3 = ev.w + er.w; e3 = e3 > 0.f ? e3 : 0.2f * e3;
                s_sid[wslot][j] = sid;
                s_ew[wslot][j] = make_float4(e0, e1, e2, e3);
                m0 = fmaxf(m0, e0); m1 = fmaxf(m1, e1);
                m2 = fmaxf(m2, e2); m3 = fmaxf(m3, e3);
            }
        }
        #pragma unroll
        for (int o = 32; o >= 1; o >>= 1) {
            m0 = fmaxf(m0, __shfl_xor(m0, o)); m1 = fmaxf(m1, __shfl_xor(m1, o));
            m2 = fmaxf(m2, __shfl_xor(m2, o)); m3 = fmaxf(m3, __shfl_xor(m3, o));
        }
        float s0 = 0.f, s1 = 0.f, s2 = 0.f, s3 = 0.f;
        for (int base = 0; base < deg; base += 64) {
            int j = base + lane;
            if (j < deg) {
                float4 ev = s_ew[wslot][j];
                float p0 = __expf(ev.x - m0), p1 = __expf(ev.y - m1);
                float p2 = __expf(ev.z - m2), p3 = __expf(ev.w - m3);
                s_ew[wslot][j] = make_float4(p0, p1, p2, p3);
                s0 += p0; s1 += p1; s2 += p2; s3 += p3;
            }
        }
        #pragma unroll
        for (int o = 32; o >= 1; o >>= 1) {
            s0 += __shfl_xor(s0, o); s1 += __shfl_xor(s1, o);
            s2 += __shfl_xor(s2, o); s3 += __shfl_xor(s3, o);
        }
        float sh = hh == 0 ? s0 : hh == 1 ? s1 : hh == 2 ? s2 : s3;
        invs = (deg > 0) ? 1.f / sh : 0.f;
        const float* ewf = reinterpret_cast<const float*>(&s_ew[wslot][0]);
        // phase 2: 4-edge ILP — 4 independent gather chains
        float a0 = 0.f, a1 = 0.f, a2 = 0.f, a3 = 0.f;
        float b0 = 0.f, b1 = 0.f, b2 = 0.f, b3 = 0.f;
        int j = 0;
        const int deg4 = deg & ~3;
        for (; j < deg4; j += 4) {
            int sid0 = s_sid[wslot][j + 0];
            int sid1 = s_sid[wslot][j + 1];
            int sid2 = s_sid[wslot][j + 2];
            int sid3 = s_sid[wslot][j + 3];
            u32 h0 = h[(size_t)sid0 * 64 + lane];
            u32 h1 = h[(size_t)sid1 * 64 + lane];
            u32 h2 = h[(size_t)sid2 * 64 + lane];
            u32 h3 = h[(size_t)sid3 * 64 + lane];
            float w0 = ewf[(j + 0) * 4 + hh];
            float w1 = ewf[(j + 1) * 4 + hh];
            float w2 = ewf[(j + 2) * 4 + hh];
            float w3 = ewf[(j + 3) * 4 + hh];
            a0 = fmaf(w0, bflo(h0), a0); b0 = fmaf(w0, bfhi(h0), b0);
            a1 = fmaf(w1, bflo(h1), a1); b1 = fmaf(w1, bfhi(h1), b1);
            a2 = fmaf(w2, bflo(h2), a2); b2 = fmaf(w2, bfhi(h2), b2);
            a3 = fmaf(w3, bflo(h3), a3); b3 = fmaf(w3, bfhi(h3), b3);
        }
        for (; j < deg; ++j) {
            int sid = s_sid[wslot][j];
            float wg = ewf[j * 4 + hh];
            u32 hv = h[(size_t)sid * 64 + lane];
            a0 = fmaf(wg, bflo(hv), a0); b0 = fmaf(wg, bfhi(hv), b0);
        }
        accA = (a0 + a1) + (a2 + a3);
        accB = (b0 + b1) + (b2 + b3);
    } else {
        float er_h = hh == 0 ? er.x : hh == 1 ? er.y : hh == 2 ? er.z : er.w;
        float m = -INFINITY, s = 0.f;
        for (int p = beg; p < beg + deg; ++p) {
            int sid = csrc[p];
            float4 ev = el4[sid];
            float e = (hh == 0 ? ev.x : hh == 1 ? ev.y : hh == 2 ? ev.z : ev.w) + er_h;
            e = e > 0.f ? e : 0.2f * e;
            float nm = fmaxf(m, e);
            float f = __expf(m - nm), pe = __expf(e - nm);
            u32 hv = h[(size_t)sid * 64 + lane];
            s = s * f + pe;
            accA = accA * f + pe * bflo(hv);
            accB = accB * f + pe * bfhi(hv);
            m = nm;
        }
        invs = 1.f / s;
    }
    float oA = accA * invs + bv.x;
    float oB = accB * invs + bv.y;
    if (RELU) { oA = fmaxf(oA, 0.f); oB = fmaxf(oB, 0.f); }
    out[(size_t)wid * 64 + lane] = ((u32)f2b(oB) << 16) | (u32)f2b(oA);
}

// single-head aggregation + bias + log_softmax(40); h [N,40] bf16, out fp32
__global__ __launch_bounds__(256) void agg1v2(const u16* __restrict__ h,
                                              const float* __restrict__ el,
                                              const float* __restrict__ er,
                                              const float* __restrict__ bias,
                                              const int* __restrict__ rowptr,
                                              const int* __restrict__ csrc,
                                              float* __restrict__ out, int N) {
    __shared__ float s_ew[4][CAP];
    __shared__ int s_sid[4][CAP];
    const int wslot = threadIdx.x >> 6, lane = threadIdx.x & 63;
    const int wid = blockIdx.x * 4 + wslot;
    if (wid >= N) return;
    const int beg = rowptr[wid];
    const int deg = rowptr[wid + 1] - beg;
    const float ern = er[wid];
    const int ll = lane < 40 ? lane : 39;   // clamp: same cache line, no extra fetch
    float acc = 0.f, invs;

    if (deg <= CAP) {
        float m = -INFINITY;
        for (int base = 0; base < deg; base += 64) {
            int j = base + lane;
            if (j < deg) {
                int sid = csrc[beg + j];
                float e = el[sid] + ern; e = e > 0.f ? e : 0.2f * e;
                s_sid[wslot][j] = sid;
                s_ew[wslot][j] = e;
                m = fmaxf(m, e);
            }
        }
        #pragma unroll
        for (int o = 32; o >= 1; o >>= 1) m = fmaxf(m, __shfl_xor(m, o));
        float s = 0.f;
        for (int base = 0; base < deg; base += 64) {
            int j = base + lane;
            if (j < deg) {
                float p = __expf(s_ew[wslot][j] - m);
                s_ew[wslot][j] = p;
                s += p;
            }
        }
        #pragma unroll
        for (int o = 32; o >= 1; o >>= 1) s += __shfl_xor(s, o);
        invs = (deg > 0) ? 1.f / s : 0.f;
        // phase 2: 4-edge ILP
        float a0 = 0.f, a1 = 0.f, a2 = 0.f, a3 = 0.f;
        int j = 0;
        const int deg4 = deg & ~3;
        for (; j < deg4; j += 4) {
            int sid0 = s_sid[wslot][j + 0];
            int sid1 = s_sid[wslot][j + 1];
            int sid2 = s_sid[wslot][j + 2];
            int sid3 = s_sid[wslot][j + 3];
            float x0 = b2f(h[(size_t)sid0 * 40 + ll]);
            float x1 = b2f(h[(size_t)sid1 * 40 + ll]);
            float x2 = b2f(h[(size_t)sid2 * 40 + ll]);
            float x3 = b2f(h[(size_t)sid3 * 40 + ll]);
            float w0 = s_ew[wslot][j + 0];
            float w1 = s_ew[wslot][j + 1];
            float w2 = s_ew[wslot][j + 2];
            float w3 = s_ew[wslot][j + 3];
            a0 = fmaf(w0, x0, a0);
            a1 = fmaf(w1, x1, a1);
            a2 = fmaf(w2, x2, a2);
            a3 = fmaf(w3, x3, a3);
        }
        for (; j < deg; ++j) {
            int sid = s_sid[wslot][j];
            a0 = fmaf(s_ew[wslot][j], b2f(h[(size_t)sid * 40 + ll]), a0);
        }
        acc = (a0 + a1) + (a2 + a3);
    } else {
        float m = -INFINITY, s = 0.f;
        for (int p = beg; p < beg + deg; ++p) {
            int sid = csrc[p];
            float e = el[sid] + ern; e = e > 0.f ? e : 0.2f * e;
            float nm = fmaxf(m, e);
            float f = __expf(m - nm), pe = __expf(e - nm);
            float hx = b2f(h[(size_t)sid * 40 + ll]);
            s = s * f + pe;
            acc = acc * f + pe * hx;
            m = nm;
        }
        invs = 1.f / s;
    }
    float v = acc * invs + ((lane < 40) ? bias[lane] : 0.f);
    float vv = (lane < 40) ? v : -INFINITY;
    float mx = vv;
    #pragma unroll
    for (int o = 32; o >= 1; o >>= 1) mx = fmaxf(mx, __shfl_xor(mx, o));
    float ex = (lane < 40) ? __expf(v - mx) : 0.f;
    float se = ex;
    #pragma unroll
    for (int o = 32; o >= 1; o >>= 1) se += __shfl_xor(se, o);
    if (lane < 40) out[(size_t)wid * 40 + lane] = v - mx - logf(se);
}

// ============================== launch ==============================

extern "C" void kernel_launch(void* const* d_in, const int* in_sizes, int n_in,
                              void* d_out, int out_size, void* d_ws, size_t ws_size,
                              hipStream_t stream) {
    const float* feat = (const float*)d_in[0];
    const float* W1  = (const float*)d_in[1];
    const float* al1 = (const float*)d_in[2];
    const float* ar1 = (const float*)d_in[3];
    const float* b1  = (const float*)d_in[4];
    const float* W2  = (const float*)d_in[5];
    const float* al2 = (const float*)d_in[6];
    const float* ar2 = (const float*)d_in[7];
    const float* b2  = (const float*)d_in[8];
    const float* W3  = (const float*)d_in[9];
    const float* al3 = (const float*)d_in[10];
    const float* ar3 = (const float*)d_in[11];
    const float* b3  = (const float*)d_in[12];
    const int*   src = (const int*)d_in[13];
    const int*   dst = (const int*)d_in[14];
    float* out = (float*)d_out;
    const int N = NN, E = NE;

    char* ws = (char*)d_ws;
    size_t off = 0;
    auto alloc = [&](size_t bytes) -> char* {
        char* p = ws + off;
        off += (bytes + 255) & ~(size_t)255;
        return p;
    };
    int* deg    = (int*)alloc((size_t)N * 4);
    int* rowptr = (int*)alloc((size_t)(N + 1) * 4);
    int* bsum   = (int*)alloc(512 * 4);
    int* csrc   = (int*)alloc((size_t)E * 4);
    float* el   = (float*)alloc((size_t)N * 4 * 4);
    float* er   = (float*)alloc((size_t)N * 4 * 4);
    u16* hb     = (u16*)alloc((size_t)N * 128 * 2);
    u16* xb     = (u16*)alloc((size_t)N * 128 * 2);
    u16* h3     = (u16*)alloc((size_t)N * 40 * 2 + 256);
    u16* W1t    = (u16*)alloc((size_t)128 * 256 * 2);
    u16* W2t    = (u16*)alloc((size_t)128 * 128 * 2);
    u16* W3t    = (u16*)alloc((size_t)48 * 128 * 2);

    // ---- CSR build ----
    hipMemsetAsync(deg, 0, (size_t)N * 4, stream);
    hist_kernel<<<(E + 255) / 256, 256, 0, stream>>>(dst, deg, E);
    int NB = (N + 255) / 256;
    scan_local<<<NB, 256, 0, stream>>>(deg, rowptr, bsum, N);
    scan_bsum<<<1, 512, 0, stream>>>(bsum, NB);
    scan_add<<<(N + 255) / 256, 256, 0, stream>>>(rowptr, bsum, N);
    hipMemsetAsync(deg, 0, (size_t)N * 4, stream);
    scatter_kernel<<<(E + 255) / 256, 256, 0, stream>>>(src, dst, rowptr, deg, csrc, E);

    // ---- weight prep ----
    transW<<<(128 * 256 + 255) / 256, 256, 0, stream>>>(W1, W1t, 256, 128, 128);
    transW<<<(128 * 128 + 255) / 256, 256, 0, stream>>>(W2, W2t, 128, 128, 128);
    transW<<<(48 * 128 + 255) / 256, 256, 0, stream>>>(W3, W3t, 128, 40, 48);

    int gemmGrid = (N + 127) / 128;
    int nodeGrid = (N + 3) / 4;

    // ---- layer 1 ----
    gemm_mfma<256, 8, 128, true, true><<<gemmGrid, 256, 0, stream>>>(feat, W1t, hb, N);
    elr4<<<nodeGrid, 256, 0, stream>>>(hb, al1, ar1, el, er, N);
    agg4v2<true><<<nodeGrid, 256, 0, stream>>>((const u32*)hb, (const float4*)el, (const float4*)er,
                                               b1, rowptr, csrc, (u32*)xb, N);

    // ---- layer 2 ----
    gemm_mfma<128, 8, 128, true, false><<<gemmGrid, 256, 0, stream>>>(xb, W2t, hb, N);
    elr4<<<nodeGrid, 256, 0, stream>>>(hb, al2, ar2, el, er, N);
    agg4v2<true><<<nodeGrid, 256, 0, stream>>>((const u32*)hb, (const float4*)el, (const float4*)er,
                                               b2, rowptr, csrc, (u32*)xb, N);

    // ---- layer 3 (+ fused log_softmax) ----
    gemm_mfma<128, 3, 40, true, false><<<gemmGrid, 256, 0, stream>>>(xb, W3t, h3, N);
    elr1<<<nodeGrid, 256, 0, stream>>>(h3, al3, ar3, el, er, N);
    agg1v2<<<nodeGrid, 256, 0, stream>>>(h3, el, er, b3, rowptr, csrc, out, N);
}